// Round 1
// baseline (58361.798 us; speedup 1.0000x reference)
//
#include <hip/hip_runtime.h>
#include <math.h>

// ---------------------------------------------------------------------------
// SoftmaxPeepLSTM: persistent cooperative kernel, 2 grid barriers per step.
// B=64 T=512 DIN=512 H=1024 DOUT=512. bf16 MFMA (16x16x32), f32 accum.
// Phase A: gates = [x_t|h|E] @ [Wi|Wh|Wp]^T (K=2048), K split across 4 waves,
//          wave3 (E part) scaled by 1/rowsum (softmax folded into GEMM).
//          LSTM cell elementwise; c lives in registers (1/thread, persistent).
// Phase B: logits = h_new @ Wo^T, E = exp(logits) (no max-sub: logits tiny),
//          rowsum via atomics.
// Weights are register-resident MFMA fragments loaded once in the prologue.
// ---------------------------------------------------------------------------

typedef __bf16 bf16;
typedef bf16  bf16x8 __attribute__((ext_vector_type(8)));
typedef float f32x4  __attribute__((ext_vector_type(4)));

#define B_    64
#define T_    512
#define DIN_  512
#define H_    1024
#define DOUT_ 512
#define NBLK  256
#define NTHR  256

__device__ __forceinline__ bf16x8 ld8f(const float* __restrict__ p) {
  const float4 a = *(const float4*)p;
  const float4 b = *(const float4*)(p + 4);
  bf16x8 r;
  r[0]=(bf16)a.x; r[1]=(bf16)a.y; r[2]=(bf16)a.z; r[3]=(bf16)a.w;
  r[4]=(bf16)b.x; r[5]=(bf16)b.y; r[6]=(bf16)b.z; r[7]=(bf16)b.w;
  return r;
}

__device__ __forceinline__ float sigm(float x) { return 1.f / (1.f + __expf(-x)); }

// Grid barrier (all NBLK blocks co-resident: 256 blocks, 256 thr, ~21KB LDS).
__device__ __forceinline__ void gsync(unsigned* cnt, unsigned* gen) {
  __syncthreads();
  __threadfence();                       // publish this block's stores (agent scope)
  if (threadIdx.x == 0) {
    unsigned g = __hip_atomic_load(gen, __ATOMIC_ACQUIRE, __HIP_MEMORY_SCOPE_AGENT);
    unsigned a = __hip_atomic_fetch_add(cnt, 1u, __ATOMIC_ACQ_REL, __HIP_MEMORY_SCOPE_AGENT);
    if (a == NBLK - 1) {
      __hip_atomic_store(cnt, 0u, __ATOMIC_RELAXED, __HIP_MEMORY_SCOPE_AGENT);
      __hip_atomic_fetch_add(gen, 1u, __ATOMIC_RELEASE, __HIP_MEMORY_SCOPE_AGENT);
    } else {
      while (__hip_atomic_load(gen, __ATOMIC_ACQUIRE, __HIP_MEMORY_SCOPE_AGENT) == g)
        __builtin_amdgcn_s_sleep(1);
    }
  }
  __syncthreads();
  __threadfence();                       // acquire side for all threads
}

__global__ __launch_bounds__(NTHR, 1)
void lstm_kernel(const float* __restrict__ x,  const float* __restrict__ hx,
                 const float* __restrict__ cx, const float* __restrict__ yx,
                 const float* __restrict__ Wi, const float* __restrict__ bi,
                 const float* __restrict__ Wh, const float* __restrict__ bh,
                 const float* __restrict__ Wp, const float* __restrict__ bp,
                 const float* __restrict__ Wo, const float* __restrict__ bo,
                 float* __restrict__ out, char* __restrict__ ws) {
  // ---- workspace layout ----
  unsigned* cnt   = (unsigned*)ws;              // zeroed by hipMemsetAsync
  unsigned* gen   = (unsigned*)(ws + 128);
  float*    rowsum= (float*)(ws + 256);         // [2][64]
  bf16*     hbuf  = (bf16*)(ws + 1024);         // [2][64*1024]
  bf16*     Eb    = (bf16*)(ws + 1024 + 2*B_*H_*2); // [64*512]

  // ---- output layout (flat concat, f32) ----
  float* out_h  = out;                          // [64][512][1024]
  float* out_y  = out + (size_t)B_*T_*H_;       // [64][512][512]
  float* out_hT = out_y + (size_t)B_*T_*DOUT_;  // [64][1024]
  float* out_cT = out_hT + B_*H_;               // [64][1024]
  float* out_yT = out_cT + B_*H_;               // [64][512]

  const int tid  = threadIdx.x;
  const int bid  = blockIdx.x;
  const int w    = tid >> 6;        // wave 0..3 (K-chunk owner)
  const int lane = tid & 63;
  const int quad = lane >> 4;
  const int ln15 = lane & 15;
  // Phase A tiling: mg = 32-row batch half, ng = 8 h-columns
  const int mg = bid & 1, ng = bid >> 1;        // ng in [0,128)
  // Phase B tiling (bid<128): mg2 = 16-row group, ng2 = 16 output cols
  const int mg2 = bid & 3, ng2 = bid >> 2;

  __shared__ float lred[4][32][33];   // phase A cross-wave reduce (+1 pad)
  __shared__ float lds2[4][16][17];   // phase B reduce

  bf16* h0 = hbuf;
  bf16* h1 = hbuf + B_*H_;

  // ---------------- prologue ----------------
  {
    int gidx = bid * NTHR + tid;                // 0..65535 == B_*H_
    h0[gidx] = (bf16)hx[gidx];
    if (gidx < B_*DOUT_) Eb[gidx] = (bf16)yx[gidx];
    if (gidx < 64) { rowsum[64 + gidx] = 1.f; rowsum[gidx] = 0.f; }
  }

  // W fragments: B-operand layout, lane holds W[n = ln15(+16*ns)][k = quad*8+j].
  // n_local -> gate row: g = n>>3, hcol = ng*8 + (n&7), grow = g*H + hcol.
  bf16x8 wfrag[16][2];
  {
    const int kc = w * 512;
    #pragma unroll
    for (int ks = 0; ks < 16; ++ks) {
      #pragma unroll
      for (int ns = 0; ns < 2; ++ns) {
        const int nl   = ns*16 + ln15;
        const int grow = (nl >> 3) * H_ + ng*8 + (nl & 7);
        const int kabs = kc + ks*32 + quad*8;
        const float* p;
        if      (w == 0) p = Wi + (size_t)grow * DIN_  + kabs;
        else if (w == 3) p = Wp + (size_t)grow * DOUT_ + (kabs - 1536);
        else             p = Wh + (size_t)grow * H_    + (kabs - 512);
        wfrag[ks][ns] = ld8f(p);
      }
    }
  }
  bf16x8 wofrag[8];
  if (bid < 128) {
    #pragma unroll
    for (int ks = 0; ks < 8; ++ks) {
      const int n = ng2*16 + ln15;
      const int k = w*256 + ks*32 + quad*8;
      wofrag[ks] = ld8f(Wo + (size_t)n * H_ + k);
    }
  }

  // cell state: one (row,col) per thread, persistent in a register
  const int crow = tid >> 3, chcol = tid & 7;
  const int cb   = mg*32 + crow;
  const int ccol = ng*8  + chcol;
  float c = cx[cb * H_ + ccol];
  float bias4[4];
  #pragma unroll
  for (int g = 0; g < 4; ++g) {
    const int grow = g * H_ + ccol;
    bias4[g] = bi[grow] + bh[grow] + bp[grow];
  }

  gsync(cnt, gen);

  // ---------------- time loop ----------------
  for (int t = 0; t < T_; ++t) {
    const bf16* hbR = (t & 1) ? h1 : h0;
    bf16*       hbW = (t & 1) ? h0 : h1;
    const float* rsPrev = rowsum + ((t & 1) ^ 1) * 64;
    float*       rsCur  = rowsum + (t & 1) * 64;

    if (bid == 0 && tid < 64) rsCur[tid] = 0.f;  // zero before B(t) accumulates

    // ---- phase A: gates GEMM, K split by wave ----
    f32x4 acc[2][2];
    #pragma unroll
    for (int i = 0; i < 2; ++i)
      #pragma unroll
      for (int j = 0; j < 2; ++j)
        acc[i][j] = f32x4{0.f, 0.f, 0.f, 0.f};

    const int r0 = mg*32 + ln15, r1 = r0 + 16;

    if (w == 0) {  // x_t @ Wi^T  (f32 source, cast on the fly)
      const float* base = x + (size_t)t * DIN_;
      #pragma unroll
      for (int ks = 0; ks < 16; ++ks) {
        const int kk = ks*32 + quad*8;
        bf16x8 a0 = ld8f(base + (size_t)r0 * (T_*DIN_) + kk);
        bf16x8 a1 = ld8f(base + (size_t)r1 * (T_*DIN_) + kk);
        acc[0][0] = __builtin_amdgcn_mfma_f32_16x16x32_bf16(a0, wfrag[ks][0], acc[0][0], 0,0,0);
        acc[0][1] = __builtin_amdgcn_mfma_f32_16x16x32_bf16(a0, wfrag[ks][1], acc[0][1], 0,0,0);
        acc[1][0] = __builtin_amdgcn_mfma_f32_16x16x32_bf16(a1, wfrag[ks][0], acc[1][0], 0,0,0);
        acc[1][1] = __builtin_amdgcn_mfma_f32_16x16x32_bf16(a1, wfrag[ks][1], acc[1][1], 0,0,0);
      }
    } else {       // h @ Wh^T (w=1,2) or E @ Wp^T (w=3)
      const bf16* base; int rstr;
      if (w == 3) { base = Eb; rstr = DOUT_; }
      else        { base = hbR + (w - 1) * 512; rstr = H_; }
      #pragma unroll
      for (int ks = 0; ks < 16; ++ks) {
        const int kk = ks*32 + quad*8;
        bf16x8 a0 = *(const bf16x8*)(base + r0 * rstr + kk);
        bf16x8 a1 = *(const bf16x8*)(base + r1 * rstr + kk);
        acc[0][0] = __builtin_amdgcn_mfma_f32_16x16x32_bf16(a0, wfrag[ks][0], acc[0][0], 0,0,0);
        acc[0][1] = __builtin_amdgcn_mfma_f32_16x16x32_bf16(a0, wfrag[ks][1], acc[0][1], 0,0,0);
        acc[1][0] = __builtin_amdgcn_mfma_f32_16x16x32_bf16(a1, wfrag[ks][0], acc[1][0], 0,0,0);
        acc[1][1] = __builtin_amdgcn_mfma_f32_16x16x32_bf16(a1, wfrag[ks][1], acc[1][1], 0,0,0);
      }
    }

    // wave3 holds the E (unnormalized softmax) part: scale rows by 1/rowsum
    if (w == 3) {
      #pragma unroll
      for (int ms = 0; ms < 2; ++ms) {
        #pragma unroll
        for (int r = 0; r < 4; ++r) {
          const int brow = mg*32 + ms*16 + quad*4 + r;
          const float rinv = 1.f / rsPrev[brow];
          acc[ms][0][r] *= rinv;
          acc[ms][1][r] *= rinv;
        }
      }
    }

    // cross-wave K reduction through LDS
    #pragma unroll
    for (int ms = 0; ms < 2; ++ms)
      #pragma unroll
      for (int ns = 0; ns < 2; ++ns)
        #pragma unroll
        for (int r = 0; r < 4; ++r)
          lred[w][ms*16 + quad*4 + r][ns*16 + ln15] = acc[ms][ns][r];
    __syncthreads();

    // ---- LSTM cell (one (row,col) per thread) ----
    {
      float v[4];
      #pragma unroll
      for (int g = 0; g < 4; ++g) {
        const int cl = g*8 + chcol;
        v[g] = lred[0][crow][cl] + lred[1][crow][cl]
             + lred[2][crow][cl] + lred[3][crow][cl] + bias4[g];
      }
      const float ig = sigm(v[0]);
      const float fg = sigm(v[1]);
      const float gg = tanhf(v[2]);
      const float og = sigm(v[3]);
      c = fg * c + ig * gg;
      const float hn = og * tanhf(c);
      out_h[((size_t)cb * T_ + t) * H_ + ccol] = hn;
      hbW[cb * H_ + ccol] = (bf16)hn;
      if (t == T_ - 1) {
        out_hT[cb * H_ + ccol] = hn;
        out_cT[cb * H_ + ccol] = c;
      }
    }

    // y_seq[t-1] writer (32 blocks, 2 batch rows each)
    if (bid < 32 && t > 0) {
      const int rr = tid >> 7;            // 0..1
      const int cc = (tid & 127) * 4;     // 0,4,...,508
      const int b_ = mg*32 + ng*2 + rr;
      const float rinv = 1.f / rsPrev[b_];
      const bf16* ep = Eb + b_ * DOUT_ + cc;
      float* op = out_y + ((size_t)b_ * T_ + (t - 1)) * DOUT_ + cc;
      #pragma unroll
      for (int i = 0; i < 4; ++i) op[i] = (float)ep[i] * rinv;
    }

    gsync(cnt, gen);

    // ---- phase B: logits = h_new @ Wo^T, E = exp(logits), rowsum ----
    if (bid < 128) {
      f32x4 a2 = f32x4{0.f, 0.f, 0.f, 0.f};
      const int rowb = mg2*16 + ln15;
      #pragma unroll
      for (int ks = 0; ks < 8; ++ks) {
        const int k = w*256 + ks*32 + quad*8;
        bf16x8 af = *(const bf16x8*)(hbW + rowb * H_ + k);
        a2 = __builtin_amdgcn_mfma_f32_16x16x32_bf16(af, wofrag[ks], a2, 0,0,0);
      }
      #pragma unroll
      for (int r = 0; r < 4; ++r)
        lds2[w][quad*4 + r][ln15] = a2[r];
      __syncthreads();
      {
        const int row = tid >> 4, col = tid & 15;
        float s = lds2[0][row][col] + lds2[1][row][col]
                + lds2[2][row][col] + lds2[3][row][col] + bo[ng2*16 + col];
        const float e = __expf(s);        // no max-sub: |logits| < ~3
        const int gb = mg2*16 + row;
        Eb[gb * DOUT_ + ng2*16 + col] = (bf16)e;
        lds2[0][row][col] = e;
      }
      __syncthreads();
      if (tid < 16) {
        float s = 0.f;
        #pragma unroll
        for (int j = 0; j < 16; ++j) s += lds2[0][tid][j];
        atomicAdd(&rsCur[mg2*16 + tid], s);
      }
    }

    gsync(cnt, gen);
  }

  // ---- epilogue: y_seq[T-1] and yT ----
  if (bid < 32) {
    const int rr = tid >> 7;
    const int cc = (tid & 127) * 4;
    const int b_ = mg*32 + ng*2 + rr;
    const float* rsLast = rowsum + ((T_ - 1) & 1) * 64;
    const float rinv = 1.f / rsLast[b_];
    const bf16* ep = Eb + b_ * DOUT_ + cc;
    #pragma unroll
    for (int i = 0; i < 4; ++i) {
      const float yv = (float)ep[i] * rinv;
      out_y[((size_t)b_ * T_ + (T_ - 1)) * DOUT_ + cc + i] = yv;
      out_yT[b_ * DOUT_ + cc + i] = yv;
    }
  }
}

extern "C" void kernel_launch(void* const* d_in, const int* in_sizes, int n_in,
                              void* d_out, int out_size, void* d_ws, size_t ws_size,
                              hipStream_t stream) {
  // zero barrier state + rowsum (ws is poisoned 0xAA before every launch)
  hipMemsetAsync(d_ws, 0, 1024, stream);
  hipLaunchKernelGGL(lstm_kernel, dim3(NBLK), dim3(NTHR), 0, stream,
                     (const float*)d_in[0],  (const float*)d_in[1],
                     (const float*)d_in[2],  (const float*)d_in[3],
                     (const float*)d_in[4],  (const float*)d_in[5],
                     (const float*)d_in[6],  (const float*)d_in[7],
                     (const float*)d_in[8],  (const float*)d_in[9],
                     (const float*)d_in[10], (const float*)d_in[11],
                     (float*)d_out, (char*)d_ws);
}

// Round 2
// 21939.525 us; speedup vs baseline: 2.6601x; 2.6601x over previous
//
#include <hip/hip_runtime.h>
#include <math.h>

// ---------------------------------------------------------------------------
// SoftmaxPeepLSTM: persistent cooperative kernel, 2 grid barriers per step.
// B=64 T=512 DIN=512 H=1024 DOUT=512. bf16 MFMA (16x16x32), f32 accum.
// Round 2: contended-counter barrier replaced with distributed flag barrier
//   - arrival: each block release-stores its own 128B-spaced flag (epoch#)
//   - master (block 0): 256 threads poll 256 distinct flag lines in parallel
//   - publish: master release-stores gen; others poll gen with RELAXED agent
//     loads (no per-poll cache maintenance), one acquire fence on exit.
// Epochs come from the loop counter -> no RMW, no resets, no contention.
// ---------------------------------------------------------------------------

typedef __bf16 bf16;
typedef bf16  bf16x8 __attribute__((ext_vector_type(8)));
typedef float f32x4  __attribute__((ext_vector_type(4)));

#define B_    64
#define T_    512
#define DIN_  512
#define H_    1024
#define DOUT_ 512
#define NBLK  256
#define NTHR  256

__device__ __forceinline__ bf16x8 ld8f(const float* __restrict__ p) {
  const float4 a = *(const float4*)p;
  const float4 b = *(const float4*)(p + 4);
  bf16x8 r;
  r[0]=(bf16)a.x; r[1]=(bf16)a.y; r[2]=(bf16)a.z; r[3]=(bf16)a.w;
  r[4]=(bf16)b.x; r[5]=(bf16)b.y; r[6]=(bf16)b.z; r[7]=(bf16)b.w;
  return r;
}

__device__ __forceinline__ float sigm(float x) { return 1.f / (1.f + __expf(-x)); }

// Distributed-flag grid barrier. flags[b] at byte offset b*128; gen separate.
// ep is monotonically increasing (1,2,3,...) -- flags/gen zeroed at launch.
__device__ __forceinline__ void gsync(unsigned* flags, unsigned* gen, unsigned ep) {
  __syncthreads();
  if (blockIdx.x == 0) {
    const int tid = threadIdx.x;
    if (tid > 0) {                       // thread t waits for block t's flag
      unsigned* f = flags + (size_t)tid * 32;
      while (__hip_atomic_load(f, __ATOMIC_RELAXED, __HIP_MEMORY_SCOPE_AGENT) < ep)
        __builtin_amdgcn_s_sleep(1);
    }
    __syncthreads();
    if (tid == 0)
      __hip_atomic_store(gen, ep, __ATOMIC_RELEASE, __HIP_MEMORY_SCOPE_AGENT);
  } else {
    if (threadIdx.x == 0) {
      __hip_atomic_store(flags + (size_t)blockIdx.x * 32, ep,
                         __ATOMIC_RELEASE, __HIP_MEMORY_SCOPE_AGENT);
      while (__hip_atomic_load(gen, __ATOMIC_RELAXED, __HIP_MEMORY_SCOPE_AGENT) < ep)
        __builtin_amdgcn_s_sleep(1);
    }
  }
  __syncthreads();
  __builtin_amdgcn_fence(__ATOMIC_ACQUIRE, "agent");
}

__global__ __launch_bounds__(NTHR, 1)
void lstm_kernel(const float* __restrict__ x,  const float* __restrict__ hx,
                 const float* __restrict__ cx, const float* __restrict__ yx,
                 const float* __restrict__ Wi, const float* __restrict__ bi,
                 const float* __restrict__ Wh, const float* __restrict__ bh,
                 const float* __restrict__ Wp, const float* __restrict__ bp,
                 const float* __restrict__ Wo, const float* __restrict__ bo,
                 float* __restrict__ out, char* __restrict__ ws) {
  // ---- workspace layout (first 36864 B zeroed by hipMemsetAsync) ----
  unsigned* flags = (unsigned*)ws;              // [256] lines, 128B apart
  unsigned* gen   = (unsigned*)(ws + 32768);
  float*    rowsum= (float*)(ws + 33024);       // [2][64]
  bf16*     hbuf  = (bf16*)(ws + 36864);        // [2][64*1024]
  bf16*     Eb    = (bf16*)(ws + 36864 + 2*B_*H_*2); // [64*512]

  // ---- output layout (flat concat, f32) ----
  float* out_h  = out;                          // [64][512][1024]
  float* out_y  = out + (size_t)B_*T_*H_;       // [64][512][512]
  float* out_hT = out_y + (size_t)B_*T_*DOUT_;  // [64][1024]
  float* out_cT = out_hT + B_*H_;               // [64][1024]
  float* out_yT = out_cT + B_*H_;               // [64][512]

  const int tid  = threadIdx.x;
  const int bid  = blockIdx.x;
  const int w    = tid >> 6;        // wave 0..3 (K-chunk owner)
  const int lane = tid & 63;
  const int quad = lane >> 4;
  const int ln15 = lane & 15;
  // Phase A tiling: mg = 32-row batch half, ng = 8 h-columns
  const int mg = bid & 1, ng = bid >> 1;        // ng in [0,128)
  // Phase B tiling (bid<128): mg2 = 16-row group, ng2 = 16 output cols
  const int mg2 = bid & 3, ng2 = bid >> 2;

  __shared__ float lred[4][32][33];   // phase A cross-wave reduce (+1 pad)
  __shared__ float lds2[4][16][17];   // phase B reduce

  bf16* h0 = hbuf;
  bf16* h1 = hbuf + B_*H_;

  unsigned ep = 0;                    // barrier epoch

  // ---------------- prologue ----------------
  {
    int gidx = bid * NTHR + tid;                // 0..65535 == B_*H_
    h0[gidx] = (bf16)hx[gidx];
    if (gidx < B_*DOUT_) Eb[gidx] = (bf16)yx[gidx];
    if (gidx < 64) { rowsum[64 + gidx] = 1.f; rowsum[gidx] = 0.f; }
  }

  // W fragments: B-operand layout, lane holds W[n = ln15(+16*ns)][k = quad*8+j].
  // n_local -> gate row: g = n>>3, hcol = ng*8 + (n&7), grow = g*H + hcol.
  bf16x8 wfrag[16][2];
  {
    const int kc = w * 512;
    #pragma unroll
    for (int ks = 0; ks < 16; ++ks) {
      #pragma unroll
      for (int ns = 0; ns < 2; ++ns) {
        const int nl   = ns*16 + ln15;
        const int grow = (nl >> 3) * H_ + ng*8 + (nl & 7);
        const int kabs = kc + ks*32 + quad*8;
        const float* p;
        if      (w == 0) p = Wi + (size_t)grow * DIN_  + kabs;
        else if (w == 3) p = Wp + (size_t)grow * DOUT_ + (kabs - 1536);
        else             p = Wh + (size_t)grow * H_    + (kabs - 512);
        wfrag[ks][ns] = ld8f(p);
      }
    }
  }
  bf16x8 wofrag[8];
  if (bid < 128) {
    #pragma unroll
    for (int ks = 0; ks < 8; ++ks) {
      const int n = ng2*16 + ln15;
      const int k = w*256 + ks*32 + quad*8;
      wofrag[ks] = ld8f(Wo + (size_t)n * H_ + k);
    }
  }

  // cell state: one (row,col) per thread, persistent in a register
  const int crow = tid >> 3, chcol = tid & 7;
  const int cb   = mg*32 + crow;
  const int ccol = ng*8  + chcol;
  float c = cx[cb * H_ + ccol];
  float bias4[4];
  #pragma unroll
  for (int g = 0; g < 4; ++g) {
    const int grow = g * H_ + ccol;
    bias4[g] = bi[grow] + bh[grow] + bp[grow];
  }

  gsync(flags, gen, ++ep);

  // ---------------- time loop ----------------
  for (int t = 0; t < T_; ++t) {
    const bf16* hbR = (t & 1) ? h1 : h0;
    bf16*       hbW = (t & 1) ? h0 : h1;
    const float* rsPrev = rowsum + ((t & 1) ^ 1) * 64;
    float*       rsCur  = rowsum + (t & 1) * 64;

    if (bid == 0 && tid < 64) rsCur[tid] = 0.f;  // zero before B(t) accumulates

    // ---- phase A: gates GEMM, K split by wave ----
    f32x4 acc[2][2];
    #pragma unroll
    for (int i = 0; i < 2; ++i)
      #pragma unroll
      for (int j = 0; j < 2; ++j)
        acc[i][j] = f32x4{0.f, 0.f, 0.f, 0.f};

    const int r0 = mg*32 + ln15, r1 = r0 + 16;

    if (w == 0) {  // x_t @ Wi^T  (f32 source, cast on the fly)
      const float* base = x + (size_t)t * DIN_;
      #pragma unroll
      for (int ks = 0; ks < 16; ++ks) {
        const int kk = ks*32 + quad*8;
        bf16x8 a0 = ld8f(base + (size_t)r0 * (T_*DIN_) + kk);
        bf16x8 a1 = ld8f(base + (size_t)r1 * (T_*DIN_) + kk);
        acc[0][0] = __builtin_amdgcn_mfma_f32_16x16x32_bf16(a0, wfrag[ks][0], acc[0][0], 0,0,0);
        acc[0][1] = __builtin_amdgcn_mfma_f32_16x16x32_bf16(a0, wfrag[ks][1], acc[0][1], 0,0,0);
        acc[1][0] = __builtin_amdgcn_mfma_f32_16x16x32_bf16(a1, wfrag[ks][0], acc[1][0], 0,0,0);
        acc[1][1] = __builtin_amdgcn_mfma_f32_16x16x32_bf16(a1, wfrag[ks][1], acc[1][1], 0,0,0);
      }
    } else {       // h @ Wh^T (w=1,2) or E @ Wp^T (w=3)
      const bf16* base; int rstr;
      if (w == 3) { base = Eb; rstr = DOUT_; }
      else        { base = hbR + (w - 1) * 512; rstr = H_; }
      #pragma unroll
      for (int ks = 0; ks < 16; ++ks) {
        const int kk = ks*32 + quad*8;
        bf16x8 a0 = *(const bf16x8*)(base + r0 * rstr + kk);
        bf16x8 a1 = *(const bf16x8*)(base + r1 * rstr + kk);
        acc[0][0] = __builtin_amdgcn_mfma_f32_16x16x32_bf16(a0, wfrag[ks][0], acc[0][0], 0,0,0);
        acc[0][1] = __builtin_amdgcn_mfma_f32_16x16x32_bf16(a0, wfrag[ks][1], acc[0][1], 0,0,0);
        acc[1][0] = __builtin_amdgcn_mfma_f32_16x16x32_bf16(a1, wfrag[ks][0], acc[1][0], 0,0,0);
        acc[1][1] = __builtin_amdgcn_mfma_f32_16x16x32_bf16(a1, wfrag[ks][1], acc[1][1], 0,0,0);
      }
    }

    // wave3 holds the E (unnormalized softmax) part: scale rows by 1/rowsum
    if (w == 3) {
      #pragma unroll
      for (int ms = 0; ms < 2; ++ms) {
        #pragma unroll
        for (int r = 0; r < 4; ++r) {
          const int brow = mg*32 + ms*16 + quad*4 + r;
          const float rinv = 1.f / rsPrev[brow];
          acc[ms][0][r] *= rinv;
          acc[ms][1][r] *= rinv;
        }
      }
    }

    // cross-wave K reduction through LDS
    #pragma unroll
    for (int ms = 0; ms < 2; ++ms)
      #pragma unroll
      for (int ns = 0; ns < 2; ++ns)
        #pragma unroll
        for (int r = 0; r < 4; ++r)
          lred[w][ms*16 + quad*4 + r][ns*16 + ln15] = acc[ms][ns][r];
    __syncthreads();

    // ---- LSTM cell (one (row,col) per thread) ----
    {
      float v[4];
      #pragma unroll
      for (int g = 0; g < 4; ++g) {
        const int cl = g*8 + chcol;
        v[g] = lred[0][crow][cl] + lred[1][crow][cl]
             + lred[2][crow][cl] + lred[3][crow][cl] + bias4[g];
      }
      const float ig = sigm(v[0]);
      const float fg = sigm(v[1]);
      const float gg = tanhf(v[2]);
      const float og = sigm(v[3]);
      c = fg * c + ig * gg;
      const float hn = og * tanhf(c);
      out_h[((size_t)cb * T_ + t) * H_ + ccol] = hn;
      hbW[cb * H_ + ccol] = (bf16)hn;
      if (t == T_ - 1) {
        out_hT[cb * H_ + ccol] = hn;
        out_cT[cb * H_ + ccol] = c;
      }
    }

    // y_seq[t-1] writer (32 blocks, 2 batch rows each)
    if (bid < 32 && t > 0) {
      const int rr = tid >> 7;            // 0..1
      const int cc = (tid & 127) * 4;     // 0,4,...,508
      const int b_ = mg*32 + ng*2 + rr;
      const float rinv = 1.f / rsPrev[b_];
      const bf16* ep_ = Eb + b_ * DOUT_ + cc;
      float* op = out_y + ((size_t)b_ * T_ + (t - 1)) * DOUT_ + cc;
      #pragma unroll
      for (int i = 0; i < 4; ++i) op[i] = (float)ep_[i] * rinv;
    }

    gsync(flags, gen, ++ep);

    // ---- phase B: logits = h_new @ Wo^T, E = exp(logits), rowsum ----
    if (bid < 128) {
      f32x4 a2 = f32x4{0.f, 0.f, 0.f, 0.f};
      const int rowb = mg2*16 + ln15;
      #pragma unroll
      for (int ks = 0; ks < 8; ++ks) {
        const int k = w*256 + ks*32 + quad*8;
        bf16x8 af = *(const bf16x8*)(hbW + rowb * H_ + k);
        a2 = __builtin_amdgcn_mfma_f32_16x16x32_bf16(af, wofrag[ks], a2, 0,0,0);
      }
      #pragma unroll
      for (int r = 0; r < 4; ++r)
        lds2[w][quad*4 + r][ln15] = a2[r];
      __syncthreads();
      {
        const int row = tid >> 4, col = tid & 15;
        float s = lds2[0][row][col] + lds2[1][row][col]
                + lds2[2][row][col] + lds2[3][row][col] + bo[ng2*16 + col];
        const float e = __expf(s);        // no max-sub: |logits| < ~3
        const int gb = mg2*16 + row;
        Eb[gb * DOUT_ + ng2*16 + col] = (bf16)e;
        lds2[0][row][col] = e;
      }
      __syncthreads();
      if (tid < 16) {
        float s = 0.f;
        #pragma unroll
        for (int j = 0; j < 16; ++j) s += lds2[0][tid][j];
        atomicAdd(&rsCur[mg2*16 + tid], s);
      }
    }

    gsync(flags, gen, ++ep);
  }

  // ---- epilogue: y_seq[T-1] and yT ----
  if (bid < 32) {
    const int rr = tid >> 7;
    const int cc = (tid & 127) * 4;
    const int b_ = mg*32 + ng*2 + rr;
    const float* rsLast = rowsum + ((T_ - 1) & 1) * 64;
    const float rinv = 1.f / rsLast[b_];
    const bf16* ep_ = Eb + b_ * DOUT_ + cc;
    #pragma unroll
    for (int i = 0; i < 4; ++i) {
      const float yv = (float)ep_[i] * rinv;
      out_y[((size_t)b_ * T_ + (T_ - 1)) * DOUT_ + cc + i] = yv;
      out_yT[b_ * DOUT_ + cc + i] = yv;
    }
  }
}

extern "C" void kernel_launch(void* const* d_in, const int* in_sizes, int n_in,
                              void* d_out, int out_size, void* d_ws, size_t ws_size,
                              hipStream_t stream) {
  // zero barrier flags + gen + rowsum (ws is poisoned 0xAA before every launch)
  hipMemsetAsync(d_ws, 0, 36864, stream);
  hipLaunchKernelGGL(lstm_kernel, dim3(NBLK), dim3(NTHR), 0, stream,
                     (const float*)d_in[0],  (const float*)d_in[1],
                     (const float*)d_in[2],  (const float*)d_in[3],
                     (const float*)d_in[4],  (const float*)d_in[5],
                     (const float*)d_in[6],  (const float*)d_in[7],
                     (const float*)d_in[8],  (const float*)d_in[9],
                     (const float*)d_in[10], (const float*)d_in[11],
                     (float*)d_out, (char*)d_ws);
}